// Round 3
// baseline (776.437 us; speedup 1.0000x reference)
//
#include <hip/hip_runtime.h>
#include <stdint.h>
#include <stddef.h>

// ---------------------------------------------------------------------------
// BiLSTM pair-scorer for MI355X (gfx950) — round 3
//   bilstm: 256 wgs x 1024 thr. 4 chains/wg. Gates stay in registers:
//     - B-frags hold mixed columns {i,j} / {f,o} so update needs 1 shfl_xor
//     - bias folded into MFMA C-init; forget-bias folded into f-gate bias
//     - A-tile double-buffered (1 barrier/step), rows 4..15 never read
//       (exec-masked ds_read), 544B padded row stride (bank spread)
//     - wfrag pinned via asm to defeat rematerialization
//   mlp: single fused kernel, 1 wg per pair.
// ---------------------------------------------------------------------------

typedef short short8 __attribute__((ext_vector_type(8)));
typedef float f32x4  __attribute__((ext_vector_type(4)));

#define LSEQ    256
#define NCOL    512
#define RSTRIDE 544                 // bytes per A-tile row (512 + 32 pad)
#define BUFSZ   (16 * RSTRIDE)      // 8704 B per buffer

__device__ __forceinline__ unsigned short f2bf(float f) {
    unsigned u = __builtin_bit_cast(unsigned, f);
    u += 0x7fffu + ((u >> 16) & 1u);
    return (unsigned short)(u >> 16);
}
__device__ __forceinline__ float sigm(float x) {
    float t = __builtin_amdgcn_exp2f(-1.4426950408889634f * x);
    return __builtin_amdgcn_rcpf(1.0f + t);
}

// ---------------------------------------------------------------------------
__global__ __launch_bounds__(1024)
void bilstm_kernel(const int* __restrict__ s1, const int* __restrict__ s2,
                   const float* __restrict__ embW,
                   const float* __restrict__ Wf, const float* __restrict__ bf_,
                   const float* __restrict__ Wb, const float* __restrict__ bb_,
                   float* __restrict__ seqvec /* [512][256] f32 */) {
    const int tid  = threadIdx.x;
    const int lane = tid & 63;
    const int wave = tid >> 6;            // 0..15
    const int dir   = blockIdx.x & 1;
    const int sbase = (blockIdx.x >> 1) * 4;

    const float* __restrict__ W    = dir ? Wb  : Wf;
    const float* __restrict__ bias = dir ? bb_ : bf_;

    __shared__ char In[2 * BUFSZ];        // 17408 B, A-tiles (bf16)
    __shared__ int  tokL[4][LSEQ];        // 4 KB
    __shared__ int  lenS[4];

    // ---- zero both A-tile buffers ----
    for (int off = tid * 16; off < 2 * BUFSZ; off += 16384)
        *(short8*)(In + off) = (short8)0;

    // ---- tokens + len (waves 0..3, wave w = chain w) ----
    int mylen = 0;
    if (wave < 4) {
        const int n = sbase + wave;
        const int* src = (n & 1) ? (s2 + (size_t)(n >> 1) * LSEQ)
                                 : (s1 + (size_t)(n >> 1) * LSEQ);
        const int4 tk = *(const int4*)(src + lane * 4);
        *(int4*)&tokL[wave][lane * 4] = tk;
        int cnt = (tk.x != 0) + (tk.y != 0) + (tk.z != 0) + (tk.w != 0);
        #pragma unroll
        for (int s = 1; s < 64; s <<= 1) cnt += __shfl_xor(cnt, s, 64);
        mylen = cnt;
        if (lane == 0) lenS[wave] = cnt;
    }

    // ---- W -> bf16 B-frags, MIXED columns, pinned in registers ----
    // nt0: c<8 -> i-gate unit w*8+c ; c>=8 -> j-gate unit w*8+c-8
    // nt1: c<8 -> f-gate            ; c>=8 -> o-gate
    const int c    = lane & 15;
    const int uoff = wave * 8 + (c & 7);
    const int colnt0 = (c < 8) ? uoff : (128 + uoff);
    const int colnt1 = (c < 8) ? (256 + uoff) : (384 + uoff);
    const int kb = (lane >> 4) * 8;

    short8 wfrag[8][2];
    #pragma unroll
    for (int kk = 0; kk < 8; ++kk) {
        #pragma unroll
        for (int nt = 0; nt < 2; ++nt) {
            const int col = nt ? colnt1 : colnt0;
            short8 v;
            #pragma unroll
            for (int j = 0; j < 8; ++j)
                v[j] = (short)f2bf(W[(size_t)(kk * 32 + kb + j) * NCOL + col]);
            f32x4 tmp = __builtin_bit_cast(f32x4, v);
            asm volatile("" : "+v"(tmp));          // pin: no remat, no reload
            wfrag[kk][nt] = __builtin_bit_cast(short8, tmp);
        }
    }
    const float bias0 = bias[colnt0];
    const float bias1 = bias[colnt1] + ((c < 8) ? 1.0f : 0.0f); // forget bias

    // per-lane nonlin constants: z0 lanes c<8 = sigmoid(i), c>=8 = tanh(j)
    const bool  lo  = (c < 8);
    const float km0 = lo ? -1.4426950408889634f : -2.8853900817779268f;
    const float am0 = lo ? 1.0f : 2.0f;
    const float bm0 = lo ? 0.0f : -1.0f;
    const float KM1 = -1.4426950408889634f;
    const float KM2 = -2.8853900817779268f;

    // ---- addresses ----
    const int  arow  = c;                          // A-row this lane reads
    const int  abase = arow * RSTRIDE + (lane >> 4) * 16;
    const bool ard   = (arow < 4);
    const int  ubyte = 256 + uoff * 2;             // h slot (k=128+u), lanes<8
    const int  xoff  = wave * RSTRIDE + lane * 4;  // x stage, waves<4

    // ---- stage x0 into buf0 ----
    if (wave < 4) {
        const int idx0 = dir ? ((0 < mylen) ? (mylen - 1) : 0) : 0;
        const int tk = tokL[wave][idx0];
        const float2 xv = *(const float2*)(embW + (size_t)tk * 128 + lane * 2);
        *(unsigned*)(In + xoff) =
            (unsigned)f2bf(xv.x) | ((unsigned)f2bf(xv.y) << 16);
    }
    __syncthreads();

    const int len0 = lenS[0], len1 = lenS[1], len2 = lenS[2], len3 = lenS[3];

    float cs0 = 0.f, cs1 = 0.f, cs2 = 0.f, cs3 = 0.f;   // cell state
    float hs0 = 0.f, hs1 = 0.f, hs2 = 0.f, hs3 = 0.f;   // hidden state
    float sm0 = 0.f, sm1 = 0.f, sm2 = 0.f, sm3 = 0.f;   // h running sum

    for (int t = 0; t < LSEQ; ++t) {
        const char* bR = In + (t & 1) * BUFSZ;
        char*       bW = In + (((t & 1) ^ 1)) * BUFSZ;

        // ---- prefetch x_{t+1} (waves 0..3) ----
        float2 xv;
        if (wave < 4) {
            const int tp  = (t + 1 < LSEQ) ? t + 1 : LSEQ - 1;
            const int idx = dir ? ((tp < mylen) ? (mylen - 1 - tp) : tp) : tp;
            const int tk  = tokL[wave][idx];
            xv = *(const float2*)(embW + (size_t)tk * 128 + lane * 2);
        }

        // ---- z = [x|h] @ W, bias in C-init; rows>=4 masked off reads ----
        f32x4 a0 = {bias0, bias0, bias0, bias0};
        f32x4 a1 = {bias1, bias1, bias1, bias1};
        f32x4 b0 = {0.f, 0.f, 0.f, 0.f};
        f32x4 b1 = {0.f, 0.f, 0.f, 0.f};
        #pragma unroll
        for (int kk = 0; kk < 8; kk += 2) {
            short8 af0 = (short8)0, af1 = (short8)0;
            if (ard) {
                af0 = *(const short8*)(bR + abase + kk * 64);
                af1 = *(const short8*)(bR + abase + kk * 64 + 64);
            }
            a0 = __builtin_amdgcn_mfma_f32_16x16x32_bf16(af0, wfrag[kk][0],     a0, 0, 0, 0);
            a1 = __builtin_amdgcn_mfma_f32_16x16x32_bf16(af0, wfrag[kk][1],     a1, 0, 0, 0);
            b0 = __builtin_amdgcn_mfma_f32_16x16x32_bf16(af1, wfrag[kk + 1][0], b0, 0, 0, 0);
            b1 = __builtin_amdgcn_mfma_f32_16x16x32_bf16(af1, wfrag[kk + 1][1], b1, 0, 0, 0);
        }
        const f32x4 z0 = a0 + b0;   // i (c<8) / j (c>=8), seqs = regs 0..3
        const f32x4 z1 = a1 + b1;   // f (c<8) / o (c>=8)

        // ---- nonlinearity, all in registers ----
        f32x4 g0, g1;
        #pragma unroll
        for (int j = 0; j < 4; ++j) {
            const float e0 = __builtin_amdgcn_exp2f(km0 * z0[j]);
            g0[j] = am0 * __builtin_amdgcn_rcpf(1.0f + e0) + bm0;
            const float e1 = __builtin_amdgcn_exp2f(KM1 * z1[j]);
            g1[j] = __builtin_amdgcn_rcpf(1.0f + e1);
        }
        // partner gates: lane c<8 gets j~ and o from lane c+8
        float jt0 = __shfl_xor(g0[0], 8, 64), jt1 = __shfl_xor(g0[1], 8, 64);
        float jt2 = __shfl_xor(g0[2], 8, 64), jt3 = __shfl_xor(g0[3], 8, 64);
        float ot0 = __shfl_xor(g1[0], 8, 64), ot1 = __shfl_xor(g1[1], 8, 64);
        float ot2 = __shfl_xor(g1[2], 8, 64), ot3 = __shfl_xor(g1[3], 8, 64);

        // ---- state update (meaningful on lanes<8; others compute garbage) ----
        #define UPD(S, LEN, JT, OT)                                            \
        {                                                                      \
            const bool v = (t < LEN);                                          \
            const float nc = cs##S * g1[S] + g0[S] * JT;                       \
            const float er = __builtin_amdgcn_exp2f(KM2 * nc);                 \
            const float th = 2.0f * __builtin_amdgcn_rcpf(1.0f + er) - 1.0f;   \
            const float nh = th * OT;                                          \
            cs##S = v ? nc : cs##S;                                            \
            sm##S += v ? nh : 0.0f;                                            \
            hs##S = v ? nh : hs##S;                                            \
        }
        UPD(0, len0, jt0, ot0)
        UPD(1, len1, jt1, ot1)
        UPD(2, len2, jt2, ot2)
        UPD(3, len3, jt3, ot3)
        #undef UPD

        // ---- write h (always; masked-kept value) + stage x ----
        if (lane < 8) {
            *(unsigned short*)(bW + 0 * RSTRIDE + ubyte) = f2bf(hs0);
            *(unsigned short*)(bW + 1 * RSTRIDE + ubyte) = f2bf(hs1);
            *(unsigned short*)(bW + 2 * RSTRIDE + ubyte) = f2bf(hs2);
            *(unsigned short*)(bW + 3 * RSTRIDE + ubyte) = f2bf(hs3);
        }
        if (wave < 4) {
            *(unsigned*)(bW + xoff) =
                (unsigned)f2bf(xv.x) | ((unsigned)f2bf(xv.y) << 16);
        }
        __syncthreads();
    }

    // ---- time-mean out (permutation-invariant for bwd) ----
    if (lane < 8) {
        const int u = uoff;
        seqvec[(size_t)(sbase + 0) * 256 + dir * 128 + u] = sm0 * (1.0f / 256.0f);
        seqvec[(size_t)(sbase + 1) * 256 + dir * 128 + u] = sm1 * (1.0f / 256.0f);
        seqvec[(size_t)(sbase + 2) * 256 + dir * 128 + u] = sm2 * (1.0f / 256.0f);
        seqvec[(size_t)(sbase + 3) * 256 + dir * 128 + u] = sm3 * (1.0f / 256.0f);
    }
}

// ---------------------------------------------------------------------------
// Fused MLP: out[p] = sigmoid( relu(feats[p]@Wm + bm) . Wo + bo )
//   grid = 256 wgs (one per pair) x 256 thr; Wm rows streamed coalesced.
// ---------------------------------------------------------------------------
__global__ __launch_bounds__(256)
void mlp_kernel(const float* __restrict__ feats,
                const float* __restrict__ Wm, const float* __restrict__ bm,
                const float* __restrict__ Wo, const float* __restrict__ bo,
                float* __restrict__ out) {
    const int tid = threadIdx.x;
    const int p   = blockIdx.x;
    __shared__ float fe[512];
    __shared__ float red[4];

    *(float2*)&fe[tid * 2] = *(const float2*)(feats + (size_t)p * 512 + tid * 2);
    __syncthreads();

    const int c0 = tid * 4;
    f32x4 acc = {0.f, 0.f, 0.f, 0.f};
    #pragma unroll 8
    for (int k = 0; k < 512; ++k) {
        const f32x4 w = *(const f32x4*)(Wm + (size_t)k * 1024 + c0);
        acc += w * fe[k];
    }
    const f32x4 bm4 = *(const f32x4*)(bm + c0);
    const f32x4 wo4 = *(const f32x4*)(Wo + c0);
    float part = 0.f;
    #pragma unroll
    for (int q = 0; q < 4; ++q)
        part += fmaxf(acc[q] + bm4[q], 0.f) * wo4[q];

    #pragma unroll
    for (int s = 1; s < 64; s <<= 1) part += __shfl_xor(part, s, 64);
    if ((tid & 63) == 0) red[tid >> 6] = part;
    __syncthreads();
    if (tid == 0)
        out[p] = sigm(red[0] + red[1] + red[2] + red[3] + bo[0]);
}

// ---------------------------------------------------------------------------
extern "C" void kernel_launch(void* const* d_in, const int* in_sizes, int n_in,
                              void* d_out, int out_size, void* d_ws, size_t ws_size,
                              hipStream_t stream) {
    const int*   s1   = (const int*)d_in[0];
    const int*   s2   = (const int*)d_in[1];
    const float* embW = (const float*)d_in[2];
    const float* Wf   = (const float*)d_in[3];
    const float* bf_  = (const float*)d_in[4];
    const float* Wb   = (const float*)d_in[5];
    const float* bb_  = (const float*)d_in[6];
    const float* Wm   = (const float*)d_in[7];
    const float* bm   = (const float*)d_in[8];
    const float* Wo   = (const float*)d_in[9];
    const float* bo   = (const float*)d_in[10];

    float* seqvec = (float*)d_ws;   // 512*256 f32 = 512 KB

    bilstm_kernel<<<256, 1024, 0, stream>>>(s1, s2, embW, Wf, bf_, Wb, bb_, seqvec);
    mlp_kernel<<<256, 256, 0, stream>>>(seqvec, Wm, bm, Wo, bo, (float*)d_out);
}

// Round 4
// 398.209 us; speedup vs baseline: 1.9498x; 1.9498x over previous
//
#include <hip/hip_runtime.h>
#include <stdint.h>
#include <stddef.h>

// ---------------------------------------------------------------------------
// BiLSTM pair-scorer for MI355X (gfx950) — round 4
//   bilstm: 256 wgs x 1024 thr, 4 chains/wg.
//     Lane compaction: A-tile has 4 rows (chains); every lane reads row
//     (lane&15)&3, so D regs replicate chains into all lane groups and a
//     3-cndmask select gives each lane ONE (chain, col) gate value.
//     Nonlin / shfl / update / h-write are 1 value per lane (was 4 on
//     16/64 lanes) -> ~4x less VALU+TRANS issue.
//   mlp: 1 wg per pair x 1024 thr (thread = hid column), 2-level reduce.
// ---------------------------------------------------------------------------

typedef short short8 __attribute__((ext_vector_type(8)));
typedef float f32x4  __attribute__((ext_vector_type(4)));

#define LSEQ    256
#define NCOL    512
#define RSTRIDE 544                 // bytes per A-tile row (512 + 32 pad)
#define CBUF    (4 * RSTRIDE)       // 2176 B per buffer (4 chain rows)

__device__ __forceinline__ unsigned short f2bf(float f) {
    unsigned u = __builtin_bit_cast(unsigned, f);
    u += 0x7fffu + ((u >> 16) & 1u);
    return (unsigned short)(u >> 16);
}
__device__ __forceinline__ float sigm(float x) {
    float t = __builtin_amdgcn_exp2f(-1.4426950408889634f * x);
    return __builtin_amdgcn_rcpf(1.0f + t);
}

// ---------------------------------------------------------------------------
__global__ __launch_bounds__(1024)
void bilstm_kernel(const int* __restrict__ s1, const int* __restrict__ s2,
                   const float* __restrict__ embW,
                   const float* __restrict__ Wf, const float* __restrict__ bf_,
                   const float* __restrict__ Wb, const float* __restrict__ bb_,
                   float* __restrict__ seqvec /* [512][256] f32 */) {
    const int tid  = threadIdx.x;
    const int lane = tid & 63;
    const int wave = tid >> 6;            // 0..15
    const int dir   = blockIdx.x & 1;
    const int sbase = (blockIdx.x >> 1) * 4;

    const float* __restrict__ W    = dir ? Wb  : Wf;
    const float* __restrict__ bias = dir ? bb_ : bf_;

    __shared__ char In[2 * CBUF];         // 4352 B A-tiles (bf16, 4 rows each)
    __shared__ int  tokL[4][LSEQ];        // 4 KB
    __shared__ int  lenS[4];

    // ---- zero both A-tile buffers ----
    if (tid * 16 < 2 * CBUF) *(short8*)(In + tid * 16) = (short8)0;

    // ---- tokens + len (waves 0..3, wave w = chain w) ----
    int mylen = 0;
    if (wave < 4) {
        const int n = sbase + wave;
        const int* src = (n & 1) ? (s2 + (size_t)(n >> 1) * LSEQ)
                                 : (s1 + (size_t)(n >> 1) * LSEQ);
        const int4 tk = *(const int4*)(src + lane * 4);
        *(int4*)&tokL[wave][lane * 4] = tk;
        int cnt = (tk.x != 0) + (tk.y != 0) + (tk.z != 0) + (tk.w != 0);
        #pragma unroll
        for (int s = 1; s < 64; s <<= 1) cnt += __shfl_xor(cnt, s, 64);
        mylen = cnt;
        if (lane == 0) lenS[wave] = cnt;
    }
    __syncthreads();

    // ---- W -> bf16 B-frags, MIXED columns, pinned in registers ----
    // nt0: c<8 -> i-gate unit wave*8+c ; c>=8 -> j-gate (same unit)
    // nt1: c<8 -> f-gate               ; c>=8 -> o-gate
    const int c = lane & 15;
    const int g = lane >> 4;              // chain this lane owns post-select
    const int unit = wave * 8 + (c & 7);
    const int colnt0 = (c < 8) ? unit : (128 + unit);
    const int colnt1 = (c < 8) ? (256 + unit) : (384 + unit);
    const int kb = g * 8;

    short8 wfrag[8][2];
    #pragma unroll
    for (int kk = 0; kk < 8; ++kk) {
        #pragma unroll
        for (int nt = 0; nt < 2; ++nt) {
            const int col = nt ? colnt1 : colnt0;
            short8 v;
            #pragma unroll
            for (int j = 0; j < 8; ++j)
                v[j] = (short)f2bf(W[(size_t)(kk * 32 + kb + j) * NCOL + col]);
            f32x4 tmp = __builtin_bit_cast(f32x4, v);
            asm volatile("" : "+v"(tmp));          // pin: no remat, no reload
            wfrag[kk][nt] = __builtin_bit_cast(short8, tmp);
        }
    }
    const float bias0 = bias[colnt0];
    const float bias1 = bias[colnt1] + ((c < 8) ? 1.0f : 0.0f); // forget bias

    // per-lane nonlin constants: zc0 c<8 = sigmoid(i), c>=8 = tanh(j)
    const bool  lo  = (c < 8);
    const float km0 = lo ? -1.4426950408889634f : -2.8853900817779268f;
    const float am0 = lo ? 1.0f : 2.0f;
    const float bm0 = lo ? 0.0f : -1.0f;
    const float KM1 = -1.4426950408889634f;
    const float KM2 = -2.8853900817779268f;

    // ---- addresses ----
    const int abase = (c & 3) * RSTRIDE + g * 16;       // A-frag read base
    const int hoff  = g * RSTRIDE + 256 + unit * 2;     // h write (c<8)
    const int xoff  = wave * RSTRIDE + lane * 4;        // x stage (wave<4)

    // ---- stage x0 into buf0 ----
    if (wave < 4) {
        const int idx0 = dir ? ((0 < mylen) ? (mylen - 1) : 0) : 0;
        const int tk = tokL[wave][idx0];
        const float2 xv = *(const float2*)(embW + (size_t)tk * 128 + lane * 2);
        *(unsigned*)(In + xoff) =
            (unsigned)f2bf(xv.x) | ((unsigned)f2bf(xv.y) << 16);
    }
    __syncthreads();

    const int lenv = lenS[g];             // len of this lane's chain
    float cs = 0.f, sm = 0.f, hs = 0.f;

    auto STEP = [&](int t, const char* bR, char* bW) {
        // prefetch x_{t+1} (waves 0..3)
        float2 xv;
        if (wave < 4) {
            const int tp  = (t + 1 < LSEQ) ? t + 1 : LSEQ - 1;
            const int idx = dir ? ((tp < mylen) ? (mylen - 1 - tp) : tp) : tp;
            const int tk  = tokL[wave][idx];
            xv = *(const float2*)(embW + (size_t)tk * 128 + lane * 2);
        }

        // z = [x|h] @ W, bias in C-init; duplicated chain rows, no masks
        f32x4 a0 = {bias0, bias0, bias0, bias0};
        f32x4 a1 = {bias1, bias1, bias1, bias1};
        f32x4 b0 = {0.f, 0.f, 0.f, 0.f};
        f32x4 b1 = {0.f, 0.f, 0.f, 0.f};
        #pragma unroll
        for (int kk = 0; kk < 8; kk += 2) {
            const short8 af0 = *(const short8*)(bR + abase + kk * 64);
            const short8 af1 = *(const short8*)(bR + abase + kk * 64 + 64);
            a0 = __builtin_amdgcn_mfma_f32_16x16x32_bf16(af0, wfrag[kk][0],     a0, 0, 0, 0);
            a1 = __builtin_amdgcn_mfma_f32_16x16x32_bf16(af0, wfrag[kk][1],     a1, 0, 0, 0);
            b0 = __builtin_amdgcn_mfma_f32_16x16x32_bf16(af1, wfrag[kk + 1][0], b0, 0, 0, 0);
            b1 = __builtin_amdgcn_mfma_f32_16x16x32_bf16(af1, wfrag[kk + 1][1], b1, 0, 0, 0);
        }
        const f32x4 z0 = a0 + b0;   // reg j = chain j (replicated to all groups)
        const f32x4 z1 = a1 + b1;

        // compact: this lane keeps chain g only
        const float zc0 = (g < 2) ? ((g == 0) ? z0[0] : z0[1])
                                  : ((g == 2) ? z0[2] : z0[3]);
        const float zc1 = (g < 2) ? ((g == 0) ? z1[0] : z1[1])
                                  : ((g == 2) ? z1[2] : z1[3]);

        // nonlin: one value per lane
        const float e0  = __builtin_amdgcn_exp2f(km0 * zc0);
        const float g0v = am0 * __builtin_amdgcn_rcpf(1.0f + e0) + bm0;  // i or tanh(j)
        const float e1  = __builtin_amdgcn_exp2f(KM1 * zc1);
        const float g1v = __builtin_amdgcn_rcpf(1.0f + e1);              // f or o

        // partner gates from lane c^8
        const float jt = __shfl_xor(g0v, 8, 64);
        const float ot = __shfl_xor(g1v, 8, 64);

        // state update (meaningful on c<8 lanes)
        const bool  v  = (t < lenv);
        const float nc = cs * g1v + g0v * jt;
        const float er = __builtin_amdgcn_exp2f(KM2 * nc);
        const float th = 2.0f * __builtin_amdgcn_rcpf(1.0f + er) - 1.0f;
        const float nh = th * ot;
        cs = v ? nc : cs;
        sm += v ? nh : 0.0f;
        hs = v ? nh : hs;

        // write h (frozen value when masked) + stage x
        if (c < 8) *(unsigned short*)(bW + hoff) = f2bf(hs);
        if (wave < 4)
            *(unsigned*)(bW + xoff) =
                (unsigned)f2bf(xv.x) | ((unsigned)f2bf(xv.y) << 16);
        __syncthreads();
    };

    for (int t = 0; t < LSEQ; t += 2) {
        STEP(t,     In,        In + CBUF);
        STEP(t + 1, In + CBUF, In);
    }

    // time-mean out (permutation-invariant for bwd)
    if (c < 8)
        seqvec[(size_t)(sbase + g) * 256 + dir * 128 + unit] = sm * (1.0f / 256.0f);
}

// ---------------------------------------------------------------------------
// Fused MLP: out[p] = sigmoid( relu(feats[p]@Wm + bm) . Wo + bo )
//   grid = 256 wgs (one per pair) x 1024 thr (thread = hid column)
// ---------------------------------------------------------------------------
__global__ __launch_bounds__(1024)
void mlp_kernel(const float* __restrict__ feats,
                const float* __restrict__ Wm, const float* __restrict__ bm,
                const float* __restrict__ Wo, const float* __restrict__ bo,
                float* __restrict__ out) {
    const int tid = threadIdx.x;
    const int p   = blockIdx.x;
    __shared__ float fe[512];
    __shared__ float red[16];

    if (tid < 512) fe[tid] = feats[(size_t)p * 512 + tid];
    __syncthreads();

    float a0 = 0.f, a1 = 0.f, a2 = 0.f, a3 = 0.f;
    #pragma unroll 4
    for (int k = 0; k < 512; k += 4) {
        a0 = fmaf(Wm[(size_t)(k + 0) * 1024 + tid], fe[k + 0], a0);
        a1 = fmaf(Wm[(size_t)(k + 1) * 1024 + tid], fe[k + 1], a1);
        a2 = fmaf(Wm[(size_t)(k + 2) * 1024 + tid], fe[k + 2], a2);
        a3 = fmaf(Wm[(size_t)(k + 3) * 1024 + tid], fe[k + 3], a3);
    }
    const float h = fmaxf((a0 + a1) + (a2 + a3) + bm[tid], 0.f);
    float part = h * Wo[tid];

    #pragma unroll
    for (int s = 1; s < 64; s <<= 1) part += __shfl_xor(part, s, 64);
    if ((tid & 63) == 0) red[tid >> 6] = part;
    __syncthreads();
    if (tid < 64) {
        float v = (tid < 16) ? red[tid] : 0.f;
        #pragma unroll
        for (int s = 1; s < 16; s <<= 1) v += __shfl_xor(v, s, 64);
        if (tid == 0) out[p] = sigm(v + bo[0]);
    }
}

// ---------------------------------------------------------------------------
extern "C" void kernel_launch(void* const* d_in, const int* in_sizes, int n_in,
                              void* d_out, int out_size, void* d_ws, size_t ws_size,
                              hipStream_t stream) {
    const int*   s1   = (const int*)d_in[0];
    const int*   s2   = (const int*)d_in[1];
    const float* embW = (const float*)d_in[2];
    const float* Wf   = (const float*)d_in[3];
    const float* bf_  = (const float*)d_in[4];
    const float* Wb   = (const float*)d_in[5];
    const float* bb_  = (const float*)d_in[6];
    const float* Wm   = (const float*)d_in[7];
    const float* bm   = (const float*)d_in[8];
    const float* Wo   = (const float*)d_in[9];
    const float* bo   = (const float*)d_in[10];

    float* seqvec = (float*)d_ws;   // 512*256 f32 = 512 KB

    bilstm_kernel<<<256, 1024, 0, stream>>>(s1, s2, embW, Wf, bf_, Wb, bb_, seqvec);
    mlp_kernel<<<256, 1024, 0, stream>>>(seqvec, Wm, bm, Wo, bo, (float*)d_out);
}

// Round 5
// 383.674 us; speedup vs baseline: 2.0237x; 1.0379x over previous
//
#include <hip/hip_runtime.h>
#include <stdint.h>
#include <stddef.h>

// ---------------------------------------------------------------------------
// BiLSTM pair-scorer for MI355X (gfx950) — round 5
//   bilstm: 256 wgs x 1024 thr, 4 chains/wg, lane-compacted (r4) PLUS:
//     - split-K software pipeline: z(t) = zx(t) [saved] + h(t-1)@Wh ;
//       zx(t+1) = bias + x(t+1)@Wx computed DURING step t's nonlin phase,
//       so DS/MFMA/VALU pipes overlap instead of lockstep-adding.
//     - gate re-pairing {i,j}/{f,o}: update needs ONE shfl_xor(8)
//     - tokens pre-resolved (bwd reversal done once at init)
//     - bias folded into zx C-init
//   mlp: 2-stage, col-tiled, float4 loads (was 136us of redundant L2 streams)
// ---------------------------------------------------------------------------

typedef short short8 __attribute__((ext_vector_type(8)));
typedef float f32x4  __attribute__((ext_vector_type(4)));

#define LSEQ 256
#define NCOL 512
#define RS   288                    // A-tile row stride, bytes (256 + 32 pad)
#define ABUF (4 * RS)               // 1152 B per buffer (4 chain rows)

#define MFMA(A, B, C) __builtin_amdgcn_mfma_f32_16x16x32_bf16((A), (B), (C), 0, 0, 0)

__device__ __forceinline__ unsigned short f2bf(float f) {
    unsigned u = __builtin_bit_cast(unsigned, f);
    u += 0x7fffu + ((u >> 16) & 1u);
    return (unsigned short)(u >> 16);
}
__device__ __forceinline__ float sigm(float x) {
    float t = __builtin_amdgcn_exp2f(-1.4426950408889634f * x);
    return __builtin_amdgcn_rcpf(1.0f + t);
}

// ---------------------------------------------------------------------------
__global__ __launch_bounds__(1024, 4)
void bilstm_kernel(const int* __restrict__ s1, const int* __restrict__ s2,
                   const float* __restrict__ embW,
                   const float* __restrict__ Wf, const float* __restrict__ bf_,
                   const float* __restrict__ Wb, const float* __restrict__ bb_,
                   float* __restrict__ seqvec /* [512][256] f32 */) {
    const int tid  = threadIdx.x;
    const int lane = tid & 63;
    const int wave = tid >> 6;            // 0..15
    const int dir   = blockIdx.x & 1;
    const int sbase = (blockIdx.x >> 1) * 4;

    const float* __restrict__ W    = dir ? Wb  : Wf;
    const float* __restrict__ bias = dir ? bb_ : bf_;

    __shared__ char xb[2 * ABUF];         // x_t A-tiles (bf16), 2-slot ring
    __shared__ char hb[2 * ABUF];         // h_t A-tiles (bf16), double buffer
    __shared__ int  tokRaw[4][LSEQ];
    __shared__ int  tokR[4][LSEQ];        // time-resolved token order
    __shared__ int  lenS[4];

    const int c = lane & 15;
    const int g = lane >> 4;              // chain this lane owns post-compact
    const int unit = wave * 8 + (c & 7);

    // zero hb slot1 (h(-1) = 0)
    if (tid < ABUF / 16) *(short8*)(hb + ABUF + tid * 16) = (short8)0;

    // ---- tokens: load, len, resolve order, stage x0/x1 (waves 0..3) ----
    int mylen = 0;
    if (wave < 4) {
        const int n = sbase + wave;
        const int* src = (n & 1) ? (s2 + (size_t)(n >> 1) * LSEQ)
                                 : (s1 + (size_t)(n >> 1) * LSEQ);
        const int4 tk = *(const int4*)(src + lane * 4);
        *(int4*)&tokRaw[wave][lane * 4] = tk;
        int cnt = (tk.x != 0) + (tk.y != 0) + (tk.z != 0) + (tk.w != 0);
        #pragma unroll
        for (int s = 1; s < 64; s <<= 1) cnt += __shfl_xor(cnt, s, 64);
        mylen = cnt;
        if (lane == 0) lenS[wave] = cnt;
        #pragma unroll
        for (int r = 0; r < 4; ++r) {
            const int t   = r * 64 + lane;
            const int idx = dir ? ((t < mylen) ? (mylen - 1 - t) : t) : t;
            tokR[wave][t] = tokRaw[wave][idx];
        }
        #pragma unroll
        for (int s = 0; s < 2; ++s) {
            const int tk2 = tokR[wave][s];
            const float2 xv = *(const float2*)(embW + (size_t)tk2 * 128 + lane * 2);
            *(unsigned*)(xb + s * ABUF + wave * RS + lane * 4) =
                (unsigned)f2bf(xv.x) | ((unsigned)f2bf(xv.y) << 16);
        }
    }

    // ---- W -> bf16 B-frags, re-paired columns, pinned ----
    // nt0: c<8 -> i[unit] ; c>=8 -> f[unit]   (both sigmoid; f gets +1 bias)
    // nt1: c<8 -> j[unit] ; c>=8 -> o[unit]   (tanh / sigmoid)
    const int colnt0 = (c < 8) ? unit : (256 + unit);
    const int colnt1 = (c < 8) ? (128 + unit) : (384 + unit);

    short8 wfrag[8][2];                   // kk 0..3 = x-part, 4..7 = h-part
    #pragma unroll
    for (int kk = 0; kk < 8; ++kk) {
        #pragma unroll
        for (int nt = 0; nt < 2; ++nt) {
            const int col = nt ? colnt1 : colnt0;
            short8 v;
            #pragma unroll
            for (int j = 0; j < 8; ++j)
                v[j] = (short)f2bf(W[(size_t)(kk * 32 + g * 8 + j) * NCOL + col]);
            f32x4 tmp = __builtin_bit_cast(f32x4, v);
            asm volatile("" : "+v"(tmp));          // pin: no remat/reload
            wfrag[kk][nt] = __builtin_bit_cast(short8, tmp);
        }
    }
    const float b0s = bias[colnt0] + ((c >= 8) ? 1.0f : 0.0f);
    const float b1s = bias[colnt1];
    const f32x4 biasv0 = {b0s, b0s, b0s, b0s};
    const f32x4 biasv1 = {b1s, b1s, b1s, b1s};

    // nonlin constants: zc1 is tanh on c<8 (j), sigmoid on c>=8 (o)
    const float km1 = (c < 8) ? -2.8853900817779268f : -1.4426950408889634f;
    const float a1c = (c < 8) ? 2.0f : 1.0f;
    const float b1c = (c < 8) ? -1.0f : 0.0f;
    const float KM0 = -1.4426950408889634f;
    const float KM2 = -2.8853900817779268f;

    // ---- addresses ----
    const int ard = (c & 3) * RS + g * 16;      // A-frag read base (both bufs)
    const int hwr = g * RS + unit * 2;          // h write (c>=8 lanes)
    const int xst = wave * RS + lane * 4;       // x stage (waves<4)

    __syncthreads();

    // ---- prologue: zx(0) from xb slot0 ----
    f32x4 zxa, zxb;
    {
        const short8 x0 = *(const short8*)(xb + ard);
        const short8 x1 = *(const short8*)(xb + ard + 64);
        const short8 x2 = *(const short8*)(xb + ard + 128);
        const short8 x3 = *(const short8*)(xb + ard + 192);
        zxa = MFMA(x0, wfrag[0][0], biasv0);  zxb = MFMA(x0, wfrag[0][1], biasv1);
        zxa = MFMA(x1, wfrag[1][0], zxa);     zxb = MFMA(x1, wfrag[1][1], zxb);
        zxa = MFMA(x2, wfrag[2][0], zxa);     zxb = MFMA(x2, wfrag[2][1], zxb);
        zxa = MFMA(x3, wfrag[3][0], zxa);     zxb = MFMA(x3, wfrag[3][1], zxb);
    }
    __syncthreads();   // xb slot0 free for restage; hb[1] zero visible

    const int lenv = lenS[g];
    float cs = 0.f, sm = 0.f, hs = 0.f;

    // STEP(t): reads h(t-1) from hb[P^1], writes h(t) to hb[P];
    //          reads x(t+1) from xb[P^1], stages x(t+2) to xb[P]. (P = t&1)
    auto STEP = [&](int t, const char* hR, char* hW, const char* xR, char* xW) {
        // issue x(t+2) gather early (hides under Phase A+B)
        float2 xv;
        if (wave < 4) {
            const int tp = (t + 2 < LSEQ) ? t + 2 : LSEQ - 1;
            const int tk = tokR[wave][tp];
            xv = *(const float2*)(embW + (size_t)tk * 128 + lane * 2);
        }

        // ---- Phase A: z(t) = zx(t) + h(t-1) @ Wh ----
        const short8 h0 = *(const short8*)(hR + ard);
        const short8 h1 = *(const short8*)(hR + ard + 64);
        const short8 h2 = *(const short8*)(hR + ard + 128);
        const short8 h3 = *(const short8*)(hR + ard + 192);
        f32x4 a = MFMA(h0, wfrag[4][0], zxa);
        f32x4 b = MFMA(h0, wfrag[4][1], zxb);
        a = MFMA(h1, wfrag[5][0], a);  b = MFMA(h1, wfrag[5][1], b);
        a = MFMA(h2, wfrag[6][0], a);  b = MFMA(h2, wfrag[6][1], b);
        a = MFMA(h3, wfrag[7][0], a);  b = MFMA(h3, wfrag[7][1], b);

        // compact: keep chain g
        const float zc0 = (g < 2) ? ((g == 0) ? a[0] : a[1])
                                  : ((g == 2) ? a[2] : a[3]);
        const float zc1 = (g < 2) ? ((g == 0) ? b[0] : b[1])
                                  : ((g == 2) ? b[2] : b[3]);

        // ---- Phase B: zx(t+1) GEMM interleaved with nonlin/update ----
        const short8 x0 = *(const short8*)(xR + ard);
        const short8 x1 = *(const short8*)(xR + ard + 64);
        const short8 x2 = *(const short8*)(xR + ard + 128);
        const short8 x3 = *(const short8*)(xR + ard + 192);

        // nonlin (1 value per lane): zc0 -> sigmoid(i|f), zc1 -> tanh(j)|sig(o)
        const float e0  = __builtin_amdgcn_exp2f(KM0 * zc0);
        const float g0v = __builtin_amdgcn_rcpf(1.0f + e0);
        const float e1  = __builtin_amdgcn_exp2f(km1 * zc1);
        const float g1v = a1c * __builtin_amdgcn_rcpf(1.0f + e1) + b1c;
        const float pr  = g0v * g1v;              // c<8: sig(i)*tanh(j)
        const float prx = __shfl_xor(pr, 8, 64);  // -> state lanes (c>=8)

        zxa = MFMA(x0, wfrag[0][0], biasv0);  zxb = MFMA(x0, wfrag[0][1], biasv1);
        zxa = MFMA(x1, wfrag[1][0], zxa);     zxb = MFMA(x1, wfrag[1][1], zxb);
        zxa = MFMA(x2, wfrag[2][0], zxa);     zxb = MFMA(x2, wfrag[2][1], zxb);
        zxa = MFMA(x3, wfrag[3][0], zxa);     zxb = MFMA(x3, wfrag[3][1], zxb);

        // state update (meaningful on c>=8: g0v=sig(f), g1v=sig(o))
        const bool  v  = (t < lenv);
        const float nc = cs * g0v + prx;
        const float er = __builtin_amdgcn_exp2f(KM2 * nc);
        const float th = 2.0f * __builtin_amdgcn_rcpf(1.0f + er) - 1.0f;
        const float nh = th * g1v;
        cs = v ? nc : cs;
        sm += v ? nh : 0.0f;
        hs = v ? nh : hs;

        if (c >= 8) *(unsigned short*)(hW + hwr) = f2bf(hs);
        if (wave < 4)
            *(unsigned*)(xW + xst) =
                (unsigned)f2bf(xv.x) | ((unsigned)f2bf(xv.y) << 16);
        __syncthreads();
    };

    for (int tt = 0; tt < LSEQ; tt += 2) {
        STEP(tt,     hb + ABUF, hb,        xb + ABUF, xb);
        STEP(tt + 1, hb,        hb + ABUF, xb,        xb + ABUF);
    }

    // ---- time-mean out (state lanes c>=8; permutation-invariant for bwd) ----
    if (c >= 8)
        seqvec[(size_t)(sbase + g) * 256 + dir * 128 + unit] = sm * (1.0f / 256.0f);
}

// ---------------------------------------------------------------------------
// MLP stage 1: partials[ct][pair] = sum_{cols in tile} relu(feats@Wm+bm)*Wo
//   grid = 256 wgs (64 pair-tiles x 4 col-tiles) x 256 thr
// ---------------------------------------------------------------------------
__global__ __launch_bounds__(256)
void mlp_part(const float* __restrict__ feats,
              const float* __restrict__ Wm, const float* __restrict__ bm,
              const float* __restrict__ Wo,
              float* __restrict__ partials /* [4][256] */) {
    const int tid  = threadIdx.x;
    const int lane = tid & 63;
    const int ct   = blockIdx.x & 3;
    const int p0   = (blockIdx.x >> 2) * 4;
    const int pair = p0 + (tid >> 6);
    const int col4 = ct * 256 + lane * 4;
    __shared__ float fe[4][512];

    // stage 4 pair rows (2048 floats / 256 thr = 2 x float4)
    {
        float* fef = &fe[0][0];
        const float* src = feats + (size_t)p0 * 512;
        *(float4*)&fef[tid * 8]     = *(const float4*)(src + tid * 8);
        *(float4*)&fef[tid * 8 + 4] = *(const float4*)(src + tid * 8 + 4);
    }
    __syncthreads();

    f32x4 ac0 = {0,0,0,0}, ac1 = {0,0,0,0}, ac2 = {0,0,0,0}, ac3 = {0,0,0,0};
    for (int k = 0; k < 512; k += 4) {
        const f32x4 w0 = *(const f32x4*)(Wm + (size_t)(k + 0) * 1024 + col4);
        const f32x4 w1 = *(const f32x4*)(Wm + (size_t)(k + 1) * 1024 + col4);
        const f32x4 w2 = *(const f32x4*)(Wm + (size_t)(k + 2) * 1024 + col4);
        const f32x4 w3 = *(const f32x4*)(Wm + (size_t)(k + 3) * 1024 + col4);
        ac0 += w0 * fe[pair - p0][k + 0];
        ac1 += w1 * fe[pair - p0][k + 1];
        ac2 += w2 * fe[pair - p0][k + 2];
        ac3 += w3 * fe[pair - p0][k + 3];
    }
    const f32x4 acc = (ac0 + ac1) + (ac2 + ac3);
    const f32x4 bm4 = *(const f32x4*)(bm + col4);
    const f32x4 wo4 = *(const f32x4*)(Wo + col4);
    float part = 0.f;
    #pragma unroll
    for (int q = 0; q < 4; ++q)
        part += fmaxf(acc[q] + bm4[q], 0.f) * wo4[q];

    #pragma unroll
    for (int s = 1; s < 64; s <<= 1) part += __shfl_xor(part, s, 64);
    if (lane == 0) partials[ct * 256 + pair] = part;
}

// MLP stage 2: out[p] = sigmoid(sum_ct partials[ct][p] + bo)
__global__ __launch_bounds__(256)
void mlp_fin(const float* __restrict__ partials,
             const float* __restrict__ bo, float* __restrict__ out) {
    const int p = threadIdx.x;
    out[p] = sigm(partials[p] + partials[256 + p] + partials[512 + p] +
                  partials[768 + p] + bo[0]);
}

// ---------------------------------------------------------------------------
extern "C" void kernel_launch(void* const* d_in, const int* in_sizes, int n_in,
                              void* d_out, int out_size, void* d_ws, size_t ws_size,
                              hipStream_t stream) {
    const int*   s1   = (const int*)d_in[0];
    const int*   s2   = (const int*)d_in[1];
    const float* embW = (const float*)d_in[2];
    const float* Wf   = (const float*)d_in[3];
    const float* bf_  = (const float*)d_in[4];
    const float* Wb   = (const float*)d_in[5];
    const float* bb_  = (const float*)d_in[6];
    const float* Wm   = (const float*)d_in[7];
    const float* bm   = (const float*)d_in[8];
    const float* Wo   = (const float*)d_in[9];
    const float* bo   = (const float*)d_in[10];

    float* seqvec   = (float*)d_ws;                 // 512*256 f32 = 512 KB
    float* partials = seqvec + 512 * 256;           // 1024 f32

    bilstm_kernel<<<256, 1024, 0, stream>>>(s1, s2, embW, Wf, bf_, Wb, bb_, seqvec);
    mlp_part<<<256, 256, 0, stream>>>(seqvec, Wm, bm, Wo, partials);
    mlp_fin<<<1, 256, 0, stream>>>(partials, bo, (float*)d_out);
}

// Round 6
// 382.344 us; speedup vs baseline: 2.0307x; 1.0035x over previous
//
#include <hip/hip_runtime.h>
#include <stdint.h>
#include <stddef.h>

// ---------------------------------------------------------------------------
// BiLSTM pair-scorer for MI355X (gfx950) — round 6
//   bilstm: 256 wgs x 512 thr (8 waves), 4 chains/wg.
//     DS-pipe was the wall (r5: 168 DS instrs x 12cy = 2016cy = step wall).
//     -> 8 waves x 64 gate-cols each: DS instrs/step halve (76).
//     -> wave owns 16 units x ALL 4 gates: after compaction each lane has
//        the full i/f/j/o set for its (chain, unit) -> no shfl exchange,
//        all 64 lanes useful, single ds_write_b16 for h.
//     wfrag = 32 short8 = 128 VGPRs pinned; 2 waves/SIMD.
//   mlp: unchanged 2-stage (r5).
// ---------------------------------------------------------------------------

typedef short short8 __attribute__((ext_vector_type(8)));
typedef float f32x4  __attribute__((ext_vector_type(4)));

#define LSEQ 256
#define NCOL 512
#define RS   288                    // A-tile row stride, bytes (256 + 32 pad)
#define ABUF (4 * RS)               // 1152 B per buffer (4 chain rows)

#define MFMA(A, B, C) __builtin_amdgcn_mfma_f32_16x16x32_bf16((A), (B), (C), 0, 0, 0)

__device__ __forceinline__ unsigned short f2bf(float f) {
    unsigned u = __builtin_bit_cast(unsigned, f);
    u += 0x7fffu + ((u >> 16) & 1u);
    return (unsigned short)(u >> 16);
}
__device__ __forceinline__ float sigm(float x) {
    float t = __builtin_amdgcn_exp2f(-1.4426950408889634f * x);
    return __builtin_amdgcn_rcpf(1.0f + t);
}

// ---------------------------------------------------------------------------
__global__ __launch_bounds__(512, 2)
void bilstm_kernel(const int* __restrict__ s1, const int* __restrict__ s2,
                   const float* __restrict__ embW,
                   const float* __restrict__ Wf, const float* __restrict__ bf_,
                   const float* __restrict__ Wb, const float* __restrict__ bb_,
                   float* __restrict__ seqvec /* [512][256] f32 */) {
    const int tid  = threadIdx.x;
    const int lane = tid & 63;
    const int wave = tid >> 6;            // 0..7
    const int dir   = blockIdx.x & 1;
    const int sbase = (blockIdx.x >> 1) * 4;

    const float* __restrict__ W    = dir ? Wb  : Wf;
    const float* __restrict__ bias = dir ? bb_ : bf_;

    __shared__ char xb[2 * ABUF];         // x_t tiles (bf16), ping-pong
    __shared__ char hb[2 * ABUF];         // h_t tiles (bf16), ping-pong
    __shared__ int  tokRaw[4][LSEQ];
    __shared__ int  tokR[4][LSEQ];        // time-resolved token order
    __shared__ int  lenS[4];

    const int c = lane & 15;
    const int g = lane >> 4;              // chain this lane owns post-compact
    const int u = wave * 16 + c;          // unit 0..127 this lane owns

    // zero hb slot1 (h(-1) = 0)
    if (tid < ABUF / 16) *(short8*)(hb + ABUF + tid * 16) = (short8)0;

    // ---- tokens: load, len, resolve order, stage x0/x1 (waves 0..3) ----
    int mylen = 0;
    if (wave < 4) {
        const int n = sbase + wave;
        const int* src = (n & 1) ? (s2 + (size_t)(n >> 1) * LSEQ)
                                 : (s1 + (size_t)(n >> 1) * LSEQ);
        const int4 tk = *(const int4*)(src + lane * 4);
        *(int4*)&tokRaw[wave][lane * 4] = tk;
        int cnt = (tk.x != 0) + (tk.y != 0) + (tk.z != 0) + (tk.w != 0);
        #pragma unroll
        for (int s = 1; s < 64; s <<= 1) cnt += __shfl_xor(cnt, s, 64);
        mylen = cnt;
        if (lane == 0) lenS[wave] = cnt;
        #pragma unroll
        for (int r = 0; r < 4; ++r) {
            const int t   = r * 64 + lane;
            const int idx = dir ? ((t < mylen) ? (mylen - 1 - t) : t) : t;
            tokR[wave][t] = tokRaw[wave][idx];
        }
        #pragma unroll
        for (int s = 0; s < 2; ++s) {
            const int tk2 = tokR[wave][s];
            const float2 xv = *(const float2*)(embW + (size_t)tk2 * 128 + lane * 2);
            *(unsigned*)(xb + s * ABUF + wave * RS + lane * 4) =
                (unsigned)f2bf(xv.x) | ((unsigned)f2bf(xv.y) << 16);
        }
    }

    // ---- W -> bf16 B-frags: wave owns unit block [wave*16, +16) x 4 gates ----
    // nt: 0=i(col u), 1=j(128+u), 2=f(256+u), 3=o(384+u)
    // kk: 0..3 = x-part (k 0..127), 4..7 = h-part (k 128..255)
    short8 wfrag[8][4];
    #pragma unroll
    for (int kk = 0; kk < 8; ++kk) {
        #pragma unroll
        for (int nt = 0; nt < 4; ++nt) {
            const int col = nt * 128 + u;
            short8 v;
            #pragma unroll
            for (int j = 0; j < 8; ++j)
                v[j] = (short)f2bf(W[(size_t)(kk * 32 + g * 8 + j) * NCOL + col]);
            f32x4 tmp = __builtin_bit_cast(f32x4, v);
            asm volatile("" : "+v"(tmp));          // pin: no remat/reload
            wfrag[kk][nt] = __builtin_bit_cast(short8, tmp);
        }
    }
    const float bi = bias[u];
    const float bj = bias[128 + u];
    const float bf = bias[256 + u] + 1.0f;         // forget bias folded
    const float bo = bias[384 + u];
    const f32x4 Bi = {bi, bi, bi, bi};
    const f32x4 Bj = {bj, bj, bj, bj};
    const f32x4 Bf = {bf, bf, bf, bf};
    const f32x4 Bo = {bo, bo, bo, bo};

    const float KS = -1.4426950408889634f;   // sigmoid exp2 scale
    const float KT = -2.8853900817779268f;   // tanh exp2 scale

    // ---- addresses ----
    const int ard = (c & 3) * RS + g * 16;   // A-frag read base (both tiles)
    const int hwr = g * RS + u * 2;          // h write (all 64 lanes)
    const int xst = wave * RS + lane * 4;    // x stage (waves<4)

    __syncthreads();

    // ---- prologue: zx(0) from xb slot0 ----
    f32x4 zi, zj, zf, zo;
    {
        const short8 x0 = *(const short8*)(xb + ard);
        const short8 x1 = *(const short8*)(xb + ard + 64);
        const short8 x2 = *(const short8*)(xb + ard + 128);
        const short8 x3 = *(const short8*)(xb + ard + 192);
        zi = MFMA(x0, wfrag[0][0], Bi); zj = MFMA(x0, wfrag[0][1], Bj);
        zf = MFMA(x0, wfrag[0][2], Bf); zo = MFMA(x0, wfrag[0][3], Bo);
        zi = MFMA(x1, wfrag[1][0], zi); zj = MFMA(x1, wfrag[1][1], zj);
        zf = MFMA(x1, wfrag[1][2], zf); zo = MFMA(x1, wfrag[1][3], zo);
        zi = MFMA(x2, wfrag[2][0], zi); zj = MFMA(x2, wfrag[2][1], zj);
        zf = MFMA(x2, wfrag[2][2], zf); zo = MFMA(x2, wfrag[2][3], zo);
        zi = MFMA(x3, wfrag[3][0], zi); zj = MFMA(x3, wfrag[3][1], zj);
        zf = MFMA(x3, wfrag[3][2], zf); zo = MFMA(x3, wfrag[3][3], zo);
    }
    __syncthreads();   // xb slot0 free; hb slot1 zeros visible

    const int lenv = lenS[g];
    float cs = 0.f, sm = 0.f, hs = 0.f;

    // STEP(t): z(t) = zx(t) + h(t-1)@Wh ; zx(t+1) = bias + x(t+1)@Wx ;
    //          update; write h(t); stage x(t+2).
    auto STEP = [&](int t, const char* hR, char* hW, const char* xR, char* xW) {
        // issue x(t+2) gather early (full step to cover HBM/L3 latency)
        float2 xv;
        if (wave < 4) {
            const int tp = (t + 2 < LSEQ) ? t + 2 : LSEQ - 1;
            const int tk = tokR[wave][tp];
            xv = *(const float2*)(embW + (size_t)tk * 128 + lane * 2);
        }

        // ---- Phase A: finish z(t) with h(t-1) ----
        const short8 h0 = *(const short8*)(hR + ard);
        const short8 h1 = *(const short8*)(hR + ard + 64);
        const short8 h2 = *(const short8*)(hR + ard + 128);
        const short8 h3 = *(const short8*)(hR + ard + 192);
        f32x4 ai = MFMA(h0, wfrag[4][0], zi), aj = MFMA(h0, wfrag[4][1], zj);
        f32x4 af = MFMA(h0, wfrag[4][2], zf), ao = MFMA(h0, wfrag[4][3], zo);
        ai = MFMA(h1, wfrag[5][0], ai); aj = MFMA(h1, wfrag[5][1], aj);
        af = MFMA(h1, wfrag[5][2], af); ao = MFMA(h1, wfrag[5][3], ao);
        ai = MFMA(h2, wfrag[6][0], ai); aj = MFMA(h2, wfrag[6][1], aj);
        af = MFMA(h2, wfrag[6][2], af); ao = MFMA(h2, wfrag[6][3], ao);
        ai = MFMA(h3, wfrag[7][0], ai); aj = MFMA(h3, wfrag[7][1], aj);
        af = MFMA(h3, wfrag[7][2], af); ao = MFMA(h3, wfrag[7][3], ao);

        // compact: keep chain g (D reg j = chain j, replicated to all groups)
        const float zci = (g < 2) ? ((g == 0) ? ai[0] : ai[1]) : ((g == 2) ? ai[2] : ai[3]);
        const float zcj = (g < 2) ? ((g == 0) ? aj[0] : aj[1]) : ((g == 2) ? aj[2] : aj[3]);
        const float zcf = (g < 2) ? ((g == 0) ? af[0] : af[1]) : ((g == 2) ? af[2] : af[3]);
        const float zco = (g < 2) ? ((g == 0) ? ao[0] : ao[1]) : ((g == 2) ? ao[2] : ao[3]);

        // ---- Phase B: zx(t+1) ----
        const short8 x0 = *(const short8*)(xR + ard);
        const short8 x1 = *(const short8*)(xR + ard + 64);
        const short8 x2 = *(const short8*)(xR + ard + 128);
        const short8 x3 = *(const short8*)(xR + ard + 192);
        zi = MFMA(x0, wfrag[0][0], Bi); zj = MFMA(x0, wfrag[0][1], Bj);
        zf = MFMA(x0, wfrag[0][2], Bf); zo = MFMA(x0, wfrag[0][3], Bo);
        zi = MFMA(x1, wfrag[1][0], zi); zj = MFMA(x1, wfrag[1][1], zj);
        zf = MFMA(x1, wfrag[1][2], zf); zo = MFMA(x1, wfrag[1][3], zo);
        zi = MFMA(x2, wfrag[2][0], zi); zj = MFMA(x2, wfrag[2][1], zj);
        zf = MFMA(x2, wfrag[2][2], zf); zo = MFMA(x2, wfrag[2][3], zo);
        zi = MFMA(x3, wfrag[3][0], zi); zj = MFMA(x3, wfrag[3][1], zj);
        zf = MFMA(x3, wfrag[3][2], zf); zo = MFMA(x3, wfrag[3][3], zo);

        // ---- nonlin + update, fully in-lane (all 64 lanes useful) ----
        const float I = __builtin_amdgcn_rcpf(1.0f + __builtin_amdgcn_exp2f(KS * zci));
        const float F = __builtin_amdgcn_rcpf(1.0f + __builtin_amdgcn_exp2f(KS * zcf));
        const float O = __builtin_amdgcn_rcpf(1.0f + __builtin_amdgcn_exp2f(KS * zco));
        const float J = 2.0f * __builtin_amdgcn_rcpf(1.0f + __builtin_amdgcn_exp2f(KT * zcj)) - 1.0f;

        const bool  v  = (t < lenv);
        const float nc = cs * F + I * J;
        const float th = 2.0f * __builtin_amdgcn_rcpf(1.0f + __builtin_amdgcn_exp2f(KT * nc)) - 1.0f;
        const float nh = th * O;
        cs = v ? nc : cs;
        sm += v ? nh : 0.0f;
        hs = v ? nh : hs;

        *(unsigned short*)(hW + hwr) = f2bf(hs);
        if (wave < 4)
            *(unsigned*)(xW + xst) =
                (unsigned)f2bf(xv.x) | ((unsigned)f2bf(xv.y) << 16);
        __syncthreads();
    };

    for (int tt = 0; tt < LSEQ; tt += 2) {
        STEP(tt,     hb + ABUF, hb,        xb + ABUF, xb);
        STEP(tt + 1, hb,        hb + ABUF, xb,        xb + ABUF);
    }

    // ---- time-mean out (all lanes own distinct (chain g, unit u)) ----
    seqvec[(size_t)(sbase + g) * 256 + dir * 128 + u] = sm * (1.0f / 256.0f);
}

// ---------------------------------------------------------------------------
// MLP stage 1: partials[ct][pair] = sum_{cols in tile} relu(feats@Wm+bm)*Wo
//   grid = 256 wgs (64 pair-tiles x 4 col-tiles) x 256 thr
// ---------------------------------------------------------------------------
__global__ __launch_bounds__(256)
void mlp_part(const float* __restrict__ feats,
              const float* __restrict__ Wm, const float* __restrict__ bm,
              const float* __restrict__ Wo,
              float* __restrict__ partials /* [4][256] */) {
    const int tid  = threadIdx.x;
    const int lane = tid & 63;
    const int ct   = blockIdx.x & 3;
    const int p0   = (blockIdx.x >> 2) * 4;
    const int pair = p0 + (tid >> 6);
    const int col4 = ct * 256 + lane * 4;
    __shared__ float fe[4][512];

    {
        float* fef = &fe[0][0];
        const float* src = feats + (size_t)p0 * 512;
        *(float4*)&fef[tid * 8]     = *(const float4*)(src + tid * 8);
        *(float4*)&fef[tid * 8 + 4] = *(const float4*)(src + tid * 8 + 4);
    }
    __syncthreads();

    f32x4 ac0 = {0,0,0,0}, ac1 = {0,0,0,0}, ac2 = {0,0,0,0}, ac3 = {0,0,0,0};
    for (int k = 0; k < 512; k += 4) {
        const f32x4 w0 = *(const f32x4*)(Wm + (size_t)(k + 0) * 1024 + col4);
        const f32x4 w1 = *(const f32x4*)(Wm + (size_t)(k + 1) * 1024 + col4);
        const f32x4 w2 = *(const f32x4*)(Wm + (size_t)(k + 2) * 1024 + col4);
        const f32x4 w3 = *(const f32x4*)(Wm + (size_t)(k + 3) * 1024 + col4);
        ac0 += w0 * fe[pair - p0][k + 0];
        ac1 += w1 * fe[pair - p0][k + 1];
        ac2 += w2 * fe[pair - p0][k + 2];
        ac3 += w3 * fe[pair - p0][k + 3];
    }
    const f32x4 acc = (ac0 + ac1) + (ac2 + ac3);
    const f32x4 bm4 = *(const f32x4*)(bm + col4);
    const f32x4 wo4 = *(const f32x4*)(Wo + col4);
    float part = 0.f;
    #pragma unroll
    for (int q = 0; q < 4; ++q)
        part += fmaxf(acc[q] + bm4[q], 0.f) * wo4[q];

    #pragma unroll
    for (int s = 1; s < 64; s <<= 1) part += __shfl_xor(part, s, 64);
    if (lane == 0) partials[ct * 256 + pair] = part;
}

// MLP stage 2: out[p] = sigmoid(sum_ct partials[ct][p] + bo)
__global__ __launch_bounds__(256)
void mlp_fin(const float* __restrict__ partials,
             const float* __restrict__ bo, float* __restrict__ out) {
    const int p = threadIdx.x;
    out[p] = sigm(partials[p] + partials[256 + p] + partials[512 + p] +
                  partials[768 + p] + bo[0]);
}

// ---------------------------------------------------------------------------
extern "C" void kernel_launch(void* const* d_in, const int* in_sizes, int n_in,
                              void* d_out, int out_size, void* d_ws, size_t ws_size,
                              hipStream_t stream) {
    const int*   s1   = (const int*)d_in[0];
    const int*   s2   = (const int*)d_in[1];
    const float* embW = (const float*)d_in[2];
    const float* Wf   = (const float*)d_in[3];
    const float* bf_  = (const float*)d_in[4];
    const float* Wb   = (const float*)d_in[5];
    const float* bb_  = (const float*)d_in[6];
    const float* Wm   = (const float*)d_in[7];
    const float* bm   = (const float*)d_in[8];
    const float* Wo   = (const float*)d_in[9];
    const float* bo   = (const float*)d_in[10];

    float* seqvec   = (float*)d_ws;                 // 512*256 f32 = 512 KB
    float* partials = seqvec + 512 * 256;           // 1024 f32

    bilstm_kernel<<<256, 512, 0, stream>>>(s1, s2, embW, Wf, bf_, Wb, bb_, seqvec);
    mlp_part<<<256, 256, 0, stream>>>(seqvec, Wm, bm, Wo, partials);
    mlp_fin<<<1, 256, 0, stream>>>(partials, bo, (float*)d_out);
}